// Round 4
// baseline (2434.592 us; speedup 1.0000x reference)
//
#include <hip/hip_runtime.h>
#include <hip/hip_bf16.h>

// Problem constants (fixed by reference setup_inputs)
#define S_ROWS 4096
#define Q_ROWS 8192
#define DIM 256
#define N_SEL 19       // selection events (20 scan steps)
#define COLSPLIT 16    // phase-B column splits (4096/16 = 256 cols per block)
#define BM 128         // phase-B rows per block
#define BK 16          // phase-B k per pipeline step
#define NSTEPS 32      // 2 col-chunks x 16 k-steps
#define CB 64          // phase-C blocks
#define CT 512         // phase-C threads
#define CR 128         // phase-C rows per block
#define LCAP 128       // candidate list capacity per iteration

// Workspace layout (floats)
#define WS_INV_Q 0
#define WS_QQ    (WS_INV_Q + Q_ROWS)
#define WS_INV_S (WS_QQ + Q_ROWS)
#define WS_PP    (WS_INV_S + S_ROWS)
#define WS_TOP3P (WS_PP + S_ROWS)                  // [COLSPLIT][Q_ROWS][4]
#define WS_KTH   (WS_TOP3P + COLSPLIT * Q_ROWS * 4)
#define WS_CNT   (WS_KTH + 32)
#define WS_BAR   (WS_CNT + 32)
#define WS_LI    (WS_BAR + 32)                     // int [32*LCAP]
#define WS_LU    (WS_LI + 32 * LCAP)               // float[32*LCAP]

// ---------------------------------------------------------------------------
__global__ void norm_rows(const float* __restrict__ x, float* __restrict__ inv,
                          float* __restrict__ ssq, int nrows) {
    int w = (blockIdx.x * blockDim.x + threadIdx.x) >> 6;
    int lane = threadIdx.x & 63;
    if (w >= nrows) return;
    float4 v = reinterpret_cast<const float4*>(x + (size_t)w * DIM)[lane];
    float s = v.x * v.x + v.y * v.y + v.z * v.z + v.w * v.w;
#pragma unroll
    for (int o = 1; o < 64; o <<= 1) s += __shfl_xor(s, o, 64);
    float invn = 1.0f / sqrtf(s);
    float t = v.x * invn; float u = t * t;
    t = v.y * invn; u += t * t;
    t = v.z * invn; u += t * t;
    t = v.w * invn; u += t * t;
#pragma unroll
    for (int o = 1; o < 64; o <<= 1) u += __shfl_xor(u, o, 64);
    if (lane == 0) { inv[w] = invn; ssq[w] = u; }
}

// ---------------------------------------------------------------------------
__global__ void init_ws(unsigned* __restrict__ kth, int* __restrict__ cnt,
                        unsigned* __restrict__ bar, float* __restrict__ out, int n_extra) {
    int t = blockIdx.x * blockDim.x + threadIdx.x;
    if (t < 32) { kth[t] = 0x7F800000u; cnt[t] = 0; bar[t] = 0u; }
    if (t < n_extra) out[Q_ROWS + t] = 1.0f;
}

// ---------------------------------------------------------------------------
__device__ __forceinline__ void gl2lds16(const float* g, float* l) {
    __builtin_amdgcn_global_load_lds((const __attribute__((address_space(1))) void*)g,
                                     (__attribute__((address_space(3))) void*)l, 16, 0, 0);
}

__device__ __forceinline__ void t3ins(float (&t3)[3], float d) {
    float mx = fmaxf(fmaxf(t3[0], t3[1]), t3[2]);
    if (d < mx) {
        if (t3[0] == mx) t3[0] = d;
        else if (t3[1] == mx) t3[1] = d;
        else t3[2] = d;
    }
}

__device__ __forceinline__ float smean3(float a, float b, float c) {
    float lo = fminf(fminf(a, b), c);
    float hi = fmaxf(fmaxf(a, b), c);
    float md = fminf(fmaxf(a, b), fminf(fmaxf(b, c), fmaxf(a, c)));
    return ((lo + md) + hi) * (1.0f / 3.0f);
}

// ---------------------------------------------------------------------------
// Phase B: fp32 GEMM (raw dot, inv-scaled in epilogue) + per-row top-3.
// DMA staging (global_load_lds x16B), double-buffered BK=16 pipeline,
// XOR swizzle slot^=(row>>1)&3 (A reads conflict-free, B reads 2-way=free).
__launch_bounds__(256, 4)
__global__ void knn_support_kernel(const float* __restrict__ qf, const float* __restrict__ sf,
                                   const float* __restrict__ inv_q, const float* __restrict__ inv_s,
                                   const float* __restrict__ qq, const float* __restrict__ pp,
                                   float* __restrict__ top3part) {
    __shared__ __align__(16) float As[2][BM * BK];
    __shared__ __align__(16) float Bs[2][BM * BK];

    int b0 = blockIdx.x;
    // XCD-aware swizzle: XCD x owns rb-indices [8x, 8x+8) across all cs.
    int rbi = (b0 & 7) * 8 + ((b0 >> 3) & 7);
    int cs = b0 >> 6;
    int rb = rbi * BM;
    int tid = threadIdx.x;
    int lane = tid & 63, wv = tid >> 6;
    int tx = tid & 15, ty = tid >> 4;
    int r_in = lane >> 2, s_lane = lane & 3;

    float t3[8][3];
#pragma unroll
    for (int i = 0; i < 8; ++i) t3[i][0] = t3[i][1] = t3[i][2] = INFINITY;
    float acc[8][8];
#pragma unroll
    for (int i = 0; i < 8; ++i)
#pragma unroll
        for (int j = 0; j < 8; ++j) acc[i][j] = 0.0f;

    // stage step s into buffer s&1 (async DMA, source pre-swizzled)
    auto STAGE = [&](int s) {
        int ch = s >> 4, kt = s & 15;
        int ko = kt * BK;
        int cb = cs * 256 + ch * 128;
        float* bufA = As[s & 1];
        float* bufB = Bs[s & 1];
#pragma unroll
        for (int p = 0; p < 2; ++p) {
            int base_row = wv * 32 + p * 16;
            int row = base_row + r_in;
            int gs = s_lane ^ ((row >> 1) & 3);
            gl2lds16(qf + (size_t)(rb + row) * DIM + ko + gs * 4, bufA + base_row * BK);
            gl2lds16(sf + (size_t)(cb + row) * DIM + ko + gs * 4, bufB + base_row * BK);
        }
    };

    STAGE(0);
    __syncthreads();   // drains vmcnt for all waves' DMA

    for (int s = 0; s < NSTEPS; ++s) {
        if (s + 1 < NSTEPS) STAGE(s + 1);
        const float* A = As[s & 1];
        const float* B = Bs[s & 1];
#pragma unroll
        for (int q = 0; q < 4; ++q) {
            float4 av[8];
#pragma unroll
            for (int i = 0; i < 8; ++i) {
                int row = ty + 16 * i;
                av[i] = *reinterpret_cast<const float4*>(
                    A + row * BK + ((q ^ ((row >> 1) & 3)) << 2));
            }
#pragma unroll
            for (int jh = 0; jh < 2; ++jh) {
                float4 bv[4];
#pragma unroll
                for (int j2 = 0; j2 < 4; ++j2) {
                    int row = tx + 16 * (jh * 4 + j2);
                    bv[j2] = *reinterpret_cast<const float4*>(
                        B + row * BK + ((q ^ ((row >> 1) & 3)) << 2));
                }
#pragma unroll
                for (int i = 0; i < 8; ++i)
#pragma unroll
                    for (int j2 = 0; j2 < 4; ++j2) {
                        int j = jh * 4 + j2;
                        acc[i][j] += av[i].x * bv[j2].x;
                        acc[i][j] += av[i].y * bv[j2].y;
                        acc[i][j] += av[i].z * bv[j2].z;
                        acc[i][j] += av[i].w * bv[j2].w;
                    }
            }
        }
        if ((s & 15) == 15) {
            // epilogue for col-chunk ch: scale, distance, top-3; reset acc
            int ch = s >> 4;
            int cb = cs * 256 + ch * 128;
            float ivb[8], ppc[8];
#pragma unroll
            for (int j = 0; j < 8; ++j) {
                ivb[j] = inv_s[cb + tx + 16 * j];
                ppc[j] = pp[cb + tx + 16 * j];
            }
#pragma unroll
            for (int i = 0; i < 8; ++i) {
                int r = rb + ty + 16 * i;
                float iva = inv_q[r];
                float qqr = qq[r];
#pragma unroll
                for (int j = 0; j < 8; ++j) {
                    float dot = acc[i][j] * iva * ivb[j];
                    float d2 = qqr + ppc[j] - 2.0f * dot;
                    float d = sqrtf(fmaxf(d2, 1e-12f));
                    t3ins(t3[i], d);
                    acc[i][j] = 0.0f;
                }
            }
        }
        if (s + 1 < NSTEPS) __syncthreads();
    }

    // merge per-row top3 across the 16 tx lanes (in-wave butterfly)
#pragma unroll
    for (int off = 1; off < 16; off <<= 1) {
#pragma unroll
        for (int i = 0; i < 8; ++i) {
            float o0 = __shfl_xor(t3[i][0], off, 64);
            float o1 = __shfl_xor(t3[i][1], off, 64);
            float o2 = __shfl_xor(t3[i][2], off, 64);
            t3ins(t3[i], o0);
            t3ins(t3[i], o1);
            t3ins(t3[i], o2);
        }
    }
    if (tx == 0) {
#pragma unroll
        for (int i = 0; i < 8; ++i) {
            float* dst = top3part + ((size_t)cs * Q_ROWS + rb + ty + 16 * i) * 4;
            dst[0] = t3[i][0]; dst[1] = t3[i][1]; dst[2] = t3[i][2]; dst[3] = 0.0f;
        }
    }
}

// ---------------------------------------------------------------------------
// Phase C: 20 scan steps in one cooperative kernel, one relaxed-spin barrier
// per iteration. Candidates = per-block argmin ties published pre-barrier
// (a globally-selected row is necessarily its block's min). All cross-block
// mutable state moves through agent-scope atomics.
__global__ void iterate_select(const float* __restrict__ qf, const float* __restrict__ inv_q,
                               const float* __restrict__ qq, const float* __restrict__ top3part,
                               float* __restrict__ out, unsigned* __restrict__ kth,
                               int* __restrict__ cnt, unsigned* __restrict__ bar,
                               int* __restrict__ listI, float* __restrict__ listU) {
    __shared__ float t3s[CR][3];
    __shared__ float invs[CR], qqs[CR], scs[CR];
    __shared__ int kn[CR];
    __shared__ __align__(16) float qfc[DIM];
    __shared__ float red[CT / 64];
    __shared__ float bmin_sh;

    int tid = threadIdx.x;
    int rbase = blockIdx.x * CR;
    int lane = tid & 63, wv = tid >> 6;

    // stage: merge 16 phase-B partials for my rows; load invs/qqs
    if (tid < CR) {
        int r = rbase + tid;
        float b3[3] = {INFINITY, INFINITY, INFINITY};
        for (int csq = 0; csq < COLSPLIT; ++csq) {
            const float* p = top3part + ((size_t)csq * Q_ROWS + r) * 4;
            t3ins(b3, p[0]); t3ins(b3, p[1]); t3ins(b3, p[2]);
        }
        t3s[tid][0] = b3[0]; t3s[tid][1] = b3[1]; t3s[tid][2] = b3[2];
        invs[tid] = inv_q[r];
        qqs[tid] = qq[r];
        kn[tid] = 0;
    }
    __syncthreads();

    for (int t = 0; t <= N_SEL; ++t) {
        if (t > 0) {
            float kv = __uint_as_float(
                __hip_atomic_load(&kth[t - 1], __ATOMIC_RELAXED, __HIP_MEMORY_SCOPE_AGENT));
            int m = __hip_atomic_load(&cnt[t - 1], __ATOMIC_RELAXED, __HIP_MEMORY_SCOPE_AGENT);
            if (m > LCAP) m = LCAP;
            for (int j = 0; j < m; ++j) {
                float u = __uint_as_float(__hip_atomic_load(
                    (unsigned*)&listU[(t - 1) * LCAP + j], __ATOMIC_RELAXED, __HIP_MEMORY_SCOPE_AGENT));
                if (!(u <= kv)) continue;   // candidate not globally selected
                int c = __hip_atomic_load(&listI[(t - 1) * LCAP + j],
                                          __ATOMIC_RELAXED, __HIP_MEMORY_SCOPE_AGENT);
                if (tid == 0 && c >= rbase && c < rbase + CR) kn[c - rbase] = 1;
                if (tid < DIM) qfc[tid] = qf[(size_t)c * DIM + tid] * inv_q[c];
                __syncthreads();
                float qqc = qq[c];
                // 4 threads per row, float4 strided; scaled products (ref order)
                int row = tid >> 2, sub = tid & 3;
                const float4* rp = reinterpret_cast<const float4*>(qf + (size_t)(rbase + row) * DIM);
                const float4* cp = reinterpret_cast<const float4*>(qfc);
                float si = invs[row];
                float d = 0.0f;
#pragma unroll
                for (int i2 = 0; i2 < 16; ++i2) {
                    float4 v = rp[sub + 4 * i2];
                    float4 w = cp[sub + 4 * i2];
                    d += (v.x * si) * w.x;
                    d += (v.y * si) * w.y;
                    d += (v.z * si) * w.z;
                    d += (v.w * si) * w.w;
                }
                d += __shfl_xor(d, 1, 64);
                d += __shfl_xor(d, 2, 64);
                if (sub == 0) {
                    float d2 = qqs[row] + qqc - 2.0f * d;
                    float dist = sqrtf(fmaxf(d2, 1e-12f));
                    float b3[3] = {t3s[row][0], t3s[row][1], t3s[row][2]};
                    t3ins(b3, dist);
                    t3s[row][0] = b3[0]; t3s[row][1] = b3[1]; t3s[row][2] = b3[2];
                }
                __syncthreads();
            }
            __syncthreads();
        }

        if (t == N_SEL) {
            if (tid < CR)
                out[rbase + tid] = 1.0f - smean3(t3s[tid][0], t3s[tid][1], t3s[tid][2]);
            return;
        }

        // scores (inf = known)
        if (tid < CR)
            scs[tid] = kn[tid] ? INFINITY : smean3(t3s[tid][0], t3s[tid][1], t3s[tid][2]);
        __syncthreads();

        // block min
        float mn = (tid < CR) ? scs[tid] : INFINITY;
#pragma unroll
        for (int o = 1; o < 64; o <<= 1) mn = fminf(mn, __shfl_xor(mn, o, 64));
        if (lane == 0) red[wv] = mn;
        __syncthreads();
        if (tid == 0) {
            float v = red[0];
#pragma unroll
            for (int i = 1; i < CT / 64; ++i) v = fminf(v, red[i]);
            bmin_sh = v;
            atomicMin(&kth[t], __float_as_uint(v));   // device-scope
        }
        __syncthreads();
        float bmin = bmin_sh;
        // publish candidates (rows tied at block min)
        if (tid < CR && scs[tid] == bmin) {
            int pos = __hip_atomic_fetch_add(&cnt[t], 1, __ATOMIC_RELAXED, __HIP_MEMORY_SCOPE_AGENT);
            if (pos < LCAP) {
                __hip_atomic_store(&listI[t * LCAP + pos], rbase + tid,
                                   __ATOMIC_RELAXED, __HIP_MEMORY_SCOPE_AGENT);
                __hip_atomic_store((unsigned*)&listU[t * LCAP + pos], __float_as_uint(scs[tid]),
                                   __ATOMIC_RELAXED, __HIP_MEMORY_SCOPE_AGENT);
            }
        }
        __syncthreads();
        // barrier t: release arrive + relaxed spin + acquire fence
        if (tid == 0) {
            __hip_atomic_fetch_add(&bar[t], 1u, __ATOMIC_RELEASE, __HIP_MEMORY_SCOPE_AGENT);
            while (__hip_atomic_load(&bar[t], __ATOMIC_RELAXED, __HIP_MEMORY_SCOPE_AGENT) < CB)
                __builtin_amdgcn_s_sleep(2);
            __threadfence();
        }
        __syncthreads();
    }
}

// ---------------------------------------------------------------------------
extern "C" void kernel_launch(void* const* d_in, const int* in_sizes, int n_in,
                              void* d_out, int out_size, void* d_ws, size_t ws_size,
                              hipStream_t stream) {
    const float* sfeat = (const float*)d_in[0];
    const float* qfeat = (const float*)d_in[2];
    float* out = (float*)d_out;

    float* ws = (float*)d_ws;
    float* inv_q = ws + WS_INV_Q;
    float* qq    = ws + WS_QQ;
    float* inv_s = ws + WS_INV_S;
    float* pp    = ws + WS_PP;
    float* top3p = ws + WS_TOP3P;
    unsigned* kth = (unsigned*)(ws + WS_KTH);
    int* cnt      = (int*)(ws + WS_CNT);
    unsigned* bar = (unsigned*)(ws + WS_BAR);
    int* listI    = (int*)(ws + WS_LI);
    float* listU  = ws + WS_LU;

    int n_extra = out_size - Q_ROWS;
    if (n_extra < 0) n_extra = 0;

    norm_rows<<<Q_ROWS * 64 / 256, 256, 0, stream>>>(qfeat, inv_q, qq, Q_ROWS);
    norm_rows<<<S_ROWS * 64 / 256, 256, 0, stream>>>(sfeat, inv_s, pp, S_ROWS);
    init_ws<<<32, 256, 0, stream>>>(kth, cnt, bar, out, n_extra);
    knn_support_kernel<<<64 * COLSPLIT, 256, 0, stream>>>(qfeat, sfeat, inv_q, inv_s, qq, pp, top3p);

    const float* a0 = qfeat; const float* a1 = inv_q; const float* a2 = qq;
    const float* a3 = top3p; float* a4 = out;
    unsigned* a5 = kth; int* a6 = cnt; unsigned* a7 = bar; int* a8 = listI; float* a9 = listU;
    void* cargs[] = {&a0, &a1, &a2, &a3, &a4, &a5, &a6, &a7, &a8, &a9};
    hipLaunchCooperativeKernel(iterate_select, dim3(CB), dim3(CT), cargs, 0, stream);
}

// Round 5
// 1745.266 us; speedup vs baseline: 1.3950x; 1.3950x over previous
//
#include <hip/hip_runtime.h>
#include <hip/hip_bf16.h>

// Problem constants (fixed by reference setup_inputs)
#define S_ROWS 4096
#define Q_ROWS 8192
#define DIM 256
#define N_SEL 19       // selection events (20 scan steps)
#define COLSPLIT 16    // phase-B column splits (4096/16 = 256 cols per block)
#define BM 128         // phase-B rows per block
#define BK 16          // phase-B k per pipeline step
#define LDST 20        // LDS row stride (floats): 16B-aligned, quad-uniform
#define NSTEPS 32      // 2 col-chunks x 16 k-steps
#define CB 64          // phase-C blocks
#define CT 512         // phase-C threads
#define CR 128         // phase-C rows per block
#define LCAP 128       // candidate list capacity per iteration

// Workspace layout (floats)
#define WS_INV_Q 0
#define WS_QQ    (WS_INV_Q + Q_ROWS)
#define WS_INV_S (WS_QQ + Q_ROWS)
#define WS_PP    (WS_INV_S + S_ROWS)
#define WS_TOP3P (WS_PP + S_ROWS)                  // [COLSPLIT][Q_ROWS][4]
#define WS_KTH   (WS_TOP3P + COLSPLIT * Q_ROWS * 4)
#define WS_CNT   (WS_KTH + 32)
#define WS_BAR   (WS_CNT + 32)
#define WS_LI    (WS_BAR + 32)                     // int [32*LCAP]
#define WS_LU    (WS_LI + 32 * LCAP)               // float[32*LCAP]

// ---------------------------------------------------------------------------
__global__ void norm_rows(const float* __restrict__ x, float* __restrict__ inv,
                          float* __restrict__ ssq, int nrows) {
    int w = (blockIdx.x * blockDim.x + threadIdx.x) >> 6;
    int lane = threadIdx.x & 63;
    if (w >= nrows) return;
    float4 v = reinterpret_cast<const float4*>(x + (size_t)w * DIM)[lane];
    float s = v.x * v.x + v.y * v.y + v.z * v.z + v.w * v.w;
#pragma unroll
    for (int o = 1; o < 64; o <<= 1) s += __shfl_xor(s, o, 64);
    float invn = 1.0f / sqrtf(s);
    float t = v.x * invn; float u = t * t;
    t = v.y * invn; u += t * t;
    t = v.z * invn; u += t * t;
    t = v.w * invn; u += t * t;
#pragma unroll
    for (int o = 1; o < 64; o <<= 1) u += __shfl_xor(u, o, 64);
    if (lane == 0) { inv[w] = invn; ssq[w] = u; }
}

// ---------------------------------------------------------------------------
__global__ void init_ws(unsigned* __restrict__ kth, int* __restrict__ cnt,
                        unsigned* __restrict__ bar, float* __restrict__ out, int n_extra) {
    int t = blockIdx.x * blockDim.x + threadIdx.x;
    if (t < 32) { kth[t] = 0x7F800000u; cnt[t] = 0; bar[t] = 0u; }
    if (t < n_extra) out[Q_ROWS + t] = 1.0f;
}

// ---------------------------------------------------------------------------
__device__ __forceinline__ void t3ins(float (&t3)[3], float d) {
    float mx = fmaxf(fmaxf(t3[0], t3[1]), t3[2]);
    if (d < mx) {
        if (t3[0] == mx) t3[0] = d;
        else if (t3[1] == mx) t3[1] = d;
        else t3[2] = d;
    }
}

__device__ __forceinline__ float smean3(float a, float b, float c) {
    float lo = fminf(fminf(a, b), c);
    float hi = fmaxf(fmaxf(a, b), c);
    float md = fminf(fmaxf(a, b), fminf(fmaxf(b, c), fmaxf(a, c)));
    return ((lo + md) + hi) * (1.0f / 3.0f);
}

// ---------------------------------------------------------------------------
// Phase B: fp32 GEMM (raw dot, inv-scaled in epilogue) + per-row top-3.
// Reg-staged 2-phase pipeline: GLOAD(s+1)->regs | barrier | FMA(s) | DSWRITE(s+1).
// One barrier per k-step; normal cached vector loads (no DMA).
__launch_bounds__(256, 3)
__global__ void knn_support_kernel(const float* __restrict__ qf, const float* __restrict__ sf,
                                   const float* __restrict__ inv_q, const float* __restrict__ inv_s,
                                   const float* __restrict__ qq, const float* __restrict__ pp,
                                   float* __restrict__ top3part) {
    __shared__ __align__(16) float As[2][BM * LDST];
    __shared__ __align__(16) float Bs[2][BM * LDST];

    int b0 = blockIdx.x;
    // XCD-aware: XCD x owns rbi in [8x, 8x+8) across all cs (A-panel L2 reuse).
    int rbi = (b0 & 7) * 8 + ((b0 >> 3) & 7);
    int cs = b0 >> 6;
    int rb = rbi * BM;
    int tid = threadIdx.x;
    int tx = tid & 15, ty = tid >> 4;
    int r0 = tid >> 2, c0 = tid & 3;   // staging: thread -> (row, 16B-chunk)
    int r1 = r0 + 64;

    float t3[8][3];
#pragma unroll
    for (int i = 0; i < 8; ++i) t3[i][0] = t3[i][1] = t3[i][2] = INFINITY;
    float acc[8][8];
#pragma unroll
    for (int i = 0; i < 8; ++i)
#pragma unroll
        for (int j = 0; j < 8; ++j) acc[i][j] = 0.0f;

    float4 sA0, sA1, sB0, sB1;
    auto GLOAD = [&](int s) {
        int ch = s >> 4, kt = s & 15;
        int ko = kt * BK;
        int cb = cs * 256 + ch * 128;
        sA0 = *reinterpret_cast<const float4*>(qf + (size_t)(rb + r0) * DIM + ko + c0 * 4);
        sA1 = *reinterpret_cast<const float4*>(qf + (size_t)(rb + r1) * DIM + ko + c0 * 4);
        sB0 = *reinterpret_cast<const float4*>(sf + (size_t)(cb + r0) * DIM + ko + c0 * 4);
        sB1 = *reinterpret_cast<const float4*>(sf + (size_t)(cb + r1) * DIM + ko + c0 * 4);
    };
    auto DSWRITE = [&](int s) {
        float* bufA = As[s & 1];
        float* bufB = Bs[s & 1];
        *reinterpret_cast<float4*>(bufA + r0 * LDST + c0 * 4) = sA0;
        *reinterpret_cast<float4*>(bufA + r1 * LDST + c0 * 4) = sA1;
        *reinterpret_cast<float4*>(bufB + r0 * LDST + c0 * 4) = sB0;
        *reinterpret_cast<float4*>(bufB + r1 * LDST + c0 * 4) = sB1;
    };

    GLOAD(0);
    DSWRITE(0);
    for (int s = 0; s < NSTEPS; ++s) {
        if (s + 1 < NSTEPS) GLOAD(s + 1);
        __syncthreads();   // buf[s&1] writes visible; prior readers done
        const float* A = As[s & 1];
        const float* B = Bs[s & 1];
#pragma unroll
        for (int kk = 0; kk < BK; kk += 4) {
            float4 av[8];
#pragma unroll
            for (int i = 0; i < 8; ++i)
                av[i] = *reinterpret_cast<const float4*>(A + (ty + 16 * i) * LDST + kk);
#pragma unroll
            for (int jh = 0; jh < 2; ++jh) {
                float4 bv[4];
#pragma unroll
                for (int j2 = 0; j2 < 4; ++j2)
                    bv[j2] = *reinterpret_cast<const float4*>(B + (tx + 16 * (jh * 4 + j2)) * LDST + kk);
#pragma unroll
                for (int i = 0; i < 8; ++i)
#pragma unroll
                    for (int j2 = 0; j2 < 4; ++j2) {
                        int j = jh * 4 + j2;
                        acc[i][j] += av[i].x * bv[j2].x;
                        acc[i][j] += av[i].y * bv[j2].y;
                        acc[i][j] += av[i].z * bv[j2].z;
                        acc[i][j] += av[i].w * bv[j2].w;
                    }
            }
        }
        if ((s & 15) == 15) {
            // epilogue for col-chunk: scale, distance, top-3; reset acc
            int ch = s >> 4;
            int cb = cs * 256 + ch * 128;
            float ivb[8], ppc[8];
#pragma unroll
            for (int j = 0; j < 8; ++j) {
                ivb[j] = inv_s[cb + tx + 16 * j];
                ppc[j] = pp[cb + tx + 16 * j];
            }
#pragma unroll
            for (int i = 0; i < 8; ++i) {
                int r = rb + ty + 16 * i;
                float iva = inv_q[r];
                float qqr = qq[r];
#pragma unroll
                for (int j = 0; j < 8; ++j) {
                    float dot = acc[i][j] * iva * ivb[j];
                    float d2 = qqr + ppc[j] - 2.0f * dot;
                    float d = sqrtf(fmaxf(d2, 1e-12f));
                    t3ins(t3[i], d);
                    acc[i][j] = 0.0f;
                }
            }
        }
        if (s + 1 < NSTEPS) DSWRITE(s + 1);
    }

    // merge per-row top3 across the 16 tx lanes (in-wave butterfly)
#pragma unroll
    for (int off = 1; off < 16; off <<= 1) {
#pragma unroll
        for (int i = 0; i < 8; ++i) {
            float o0 = __shfl_xor(t3[i][0], off, 64);
            float o1 = __shfl_xor(t3[i][1], off, 64);
            float o2 = __shfl_xor(t3[i][2], off, 64);
            t3ins(t3[i], o0);
            t3ins(t3[i], o1);
            t3ins(t3[i], o2);
        }
    }
    if (tx == 0) {
#pragma unroll
        for (int i = 0; i < 8; ++i) {
            float* dst = top3part + ((size_t)cs * Q_ROWS + rb + ty + 16 * i) * 4;
            dst[0] = t3[i][0]; dst[1] = t3[i][1]; dst[2] = t3[i][2]; dst[3] = 0.0f;
        }
    }
}

// ---------------------------------------------------------------------------
// Phase C (unchanged from R4): 20 scan steps, one cooperative kernel, one
// relaxed-spin barrier per iteration; candidates = per-block argmin ties.
__global__ void iterate_select(const float* __restrict__ qf, const float* __restrict__ inv_q,
                               const float* __restrict__ qq, const float* __restrict__ top3part,
                               float* __restrict__ out, unsigned* __restrict__ kth,
                               int* __restrict__ cnt, unsigned* __restrict__ bar,
                               int* __restrict__ listI, float* __restrict__ listU) {
    __shared__ float t3s[CR][3];
    __shared__ float invs[CR], qqs[CR], scs[CR];
    __shared__ int kn[CR];
    __shared__ __align__(16) float qfc[DIM];
    __shared__ float red[CT / 64];
    __shared__ float bmin_sh;

    int tid = threadIdx.x;
    int rbase = blockIdx.x * CR;
    int lane = tid & 63, wv = tid >> 6;

    if (tid < CR) {
        int r = rbase + tid;
        float b3[3] = {INFINITY, INFINITY, INFINITY};
        for (int csq = 0; csq < COLSPLIT; ++csq) {
            const float* p = top3part + ((size_t)csq * Q_ROWS + r) * 4;
            t3ins(b3, p[0]); t3ins(b3, p[1]); t3ins(b3, p[2]);
        }
        t3s[tid][0] = b3[0]; t3s[tid][1] = b3[1]; t3s[tid][2] = b3[2];
        invs[tid] = inv_q[r];
        qqs[tid] = qq[r];
        kn[tid] = 0;
    }
    __syncthreads();

    for (int t = 0; t <= N_SEL; ++t) {
        if (t > 0) {
            float kv = __uint_as_float(
                __hip_atomic_load(&kth[t - 1], __ATOMIC_RELAXED, __HIP_MEMORY_SCOPE_AGENT));
            int m = __hip_atomic_load(&cnt[t - 1], __ATOMIC_RELAXED, __HIP_MEMORY_SCOPE_AGENT);
            if (m > LCAP) m = LCAP;
            for (int j = 0; j < m; ++j) {
                float u = __uint_as_float(__hip_atomic_load(
                    (unsigned*)&listU[(t - 1) * LCAP + j], __ATOMIC_RELAXED, __HIP_MEMORY_SCOPE_AGENT));
                if (!(u <= kv)) continue;
                int c = __hip_atomic_load(&listI[(t - 1) * LCAP + j],
                                          __ATOMIC_RELAXED, __HIP_MEMORY_SCOPE_AGENT);
                if (tid == 0 && c >= rbase && c < rbase + CR) kn[c - rbase] = 1;
                if (tid < DIM) qfc[tid] = qf[(size_t)c * DIM + tid] * inv_q[c];
                __syncthreads();
                float qqc = qq[c];
                int row = tid >> 2, sub = tid & 3;
                const float4* rp = reinterpret_cast<const float4*>(qf + (size_t)(rbase + row) * DIM);
                const float4* cp = reinterpret_cast<const float4*>(qfc);
                float si = invs[row];
                float d = 0.0f;
#pragma unroll
                for (int i2 = 0; i2 < 16; ++i2) {
                    float4 v = rp[sub + 4 * i2];
                    float4 w = cp[sub + 4 * i2];
                    d += (v.x * si) * w.x;
                    d += (v.y * si) * w.y;
                    d += (v.z * si) * w.z;
                    d += (v.w * si) * w.w;
                }
                d += __shfl_xor(d, 1, 64);
                d += __shfl_xor(d, 2, 64);
                if (sub == 0) {
                    float d2 = qqs[row] + qqc - 2.0f * d;
                    float dist = sqrtf(fmaxf(d2, 1e-12f));
                    float b3[3] = {t3s[row][0], t3s[row][1], t3s[row][2]};
                    t3ins(b3, dist);
                    t3s[row][0] = b3[0]; t3s[row][1] = b3[1]; t3s[row][2] = b3[2];
                }
                __syncthreads();
            }
            __syncthreads();
        }

        if (t == N_SEL) {
            if (tid < CR)
                out[rbase + tid] = 1.0f - smean3(t3s[tid][0], t3s[tid][1], t3s[tid][2]);
            return;
        }

        if (tid < CR)
            scs[tid] = kn[tid] ? INFINITY : smean3(t3s[tid][0], t3s[tid][1], t3s[tid][2]);
        __syncthreads();

        float mn = (tid < CR) ? scs[tid] : INFINITY;
#pragma unroll
        for (int o = 1; o < 64; o <<= 1) mn = fminf(mn, __shfl_xor(mn, o, 64));
        if (lane == 0) red[wv] = mn;
        __syncthreads();
        if (tid == 0) {
            float v = red[0];
#pragma unroll
            for (int i = 1; i < CT / 64; ++i) v = fminf(v, red[i]);
            bmin_sh = v;
            atomicMin(&kth[t], __float_as_uint(v));
        }
        __syncthreads();
        float bmin = bmin_sh;
        if (tid < CR && scs[tid] == bmin) {
            int pos = __hip_atomic_fetch_add(&cnt[t], 1, __ATOMIC_RELAXED, __HIP_MEMORY_SCOPE_AGENT);
            if (pos < LCAP) {
                __hip_atomic_store(&listI[t * LCAP + pos], rbase + tid,
                                   __ATOMIC_RELAXED, __HIP_MEMORY_SCOPE_AGENT);
                __hip_atomic_store((unsigned*)&listU[t * LCAP + pos], __float_as_uint(scs[tid]),
                                   __ATOMIC_RELAXED, __HIP_MEMORY_SCOPE_AGENT);
            }
        }
        __syncthreads();
        if (tid == 0) {
            __hip_atomic_fetch_add(&bar[t], 1u, __ATOMIC_RELEASE, __HIP_MEMORY_SCOPE_AGENT);
            while (__hip_atomic_load(&bar[t], __ATOMIC_RELAXED, __HIP_MEMORY_SCOPE_AGENT) < CB)
                __builtin_amdgcn_s_sleep(2);
            __threadfence();
        }
        __syncthreads();
    }
}

// ---------------------------------------------------------------------------
extern "C" void kernel_launch(void* const* d_in, const int* in_sizes, int n_in,
                              void* d_out, int out_size, void* d_ws, size_t ws_size,
                              hipStream_t stream) {
    const float* sfeat = (const float*)d_in[0];
    const float* qfeat = (const float*)d_in[2];
    float* out = (float*)d_out;

    float* ws = (float*)d_ws;
    float* inv_q = ws + WS_INV_Q;
    float* qq    = ws + WS_QQ;
    float* inv_s = ws + WS_INV_S;
    float* pp    = ws + WS_PP;
    float* top3p = ws + WS_TOP3P;
    unsigned* kth = (unsigned*)(ws + WS_KTH);
    int* cnt      = (int*)(ws + WS_CNT);
    unsigned* bar = (unsigned*)(ws + WS_BAR);
    int* listI    = (int*)(ws + WS_LI);
    float* listU  = ws + WS_LU;

    int n_extra = out_size - Q_ROWS;
    if (n_extra < 0) n_extra = 0;

    norm_rows<<<Q_ROWS * 64 / 256, 256, 0, stream>>>(qfeat, inv_q, qq, Q_ROWS);
    norm_rows<<<S_ROWS * 64 / 256, 256, 0, stream>>>(sfeat, inv_s, pp, S_ROWS);
    init_ws<<<32, 256, 0, stream>>>(kth, cnt, bar, out, n_extra);
    knn_support_kernel<<<64 * COLSPLIT, 256, 0, stream>>>(qfeat, sfeat, inv_q, inv_s, qq, pp, top3p);

    const float* a0 = qfeat; const float* a1 = inv_q; const float* a2 = qq;
    const float* a3 = top3p; float* a4 = out;
    unsigned* a5 = kth; int* a6 = cnt; unsigned* a7 = bar; int* a8 = listI; float* a9 = listU;
    void* cargs[] = {&a0, &a1, &a2, &a3, &a4, &a5, &a6, &a7, &a8, &a9};
    hipLaunchCooperativeKernel(iterate_select, dim3(CB), dim3(CT), cargs, 0, stream);
}

// Round 6
// 1649.771 us; speedup vs baseline: 1.4757x; 1.0579x over previous
//
#include <hip/hip_runtime.h>
#include <hip/hip_bf16.h>

// Problem constants (fixed by reference setup_inputs)
#define S_ROWS 4096
#define Q_ROWS 8192
#define DIM 256
#define N_SEL 19       // selection events (20 scan steps)
#define COLSPLIT 16    // phase-B column splits (4096/16 = 256 cols per block)
#define BM 128         // phase-B rows per block
#define LDST 36        // LDS row stride (floats)
#define CB 64          // phase-C blocks
#define CT 512         // phase-C threads
#define CR 128         // phase-C rows per block
#define LCAP 128       // candidate list capacity per iteration

// Workspace layout (floats)
#define WS_INV_Q 0
#define WS_QQ    (WS_INV_Q + Q_ROWS)
#define WS_INV_S (WS_QQ + Q_ROWS)
#define WS_PP    (WS_INV_S + S_ROWS)
#define WS_TOP3P (WS_PP + S_ROWS)                  // [COLSPLIT][Q_ROWS][4]
#define WS_KTH   (WS_TOP3P + COLSPLIT * Q_ROWS * 4)
#define WS_CNT   (WS_KTH + 32)
#define WS_BAR   (WS_CNT + 32)
#define WS_LI    (WS_BAR + 32)                     // int [32*LCAP]
#define WS_LU    (WS_LI + 32 * LCAP)               // float[32*LCAP]

// ---------------------------------------------------------------------------
__global__ void norm_rows(const float* __restrict__ x, float* __restrict__ inv,
                          float* __restrict__ ssq, int nrows) {
    int w = (blockIdx.x * blockDim.x + threadIdx.x) >> 6;
    int lane = threadIdx.x & 63;
    if (w >= nrows) return;
    float4 v = reinterpret_cast<const float4*>(x + (size_t)w * DIM)[lane];
    float s = v.x * v.x + v.y * v.y + v.z * v.z + v.w * v.w;
#pragma unroll
    for (int o = 1; o < 64; o <<= 1) s += __shfl_xor(s, o, 64);
    float invn = 1.0f / sqrtf(s);
    float t = v.x * invn; float u = t * t;
    t = v.y * invn; u += t * t;
    t = v.z * invn; u += t * t;
    t = v.w * invn; u += t * t;
#pragma unroll
    for (int o = 1; o < 64; o <<= 1) u += __shfl_xor(u, o, 64);
    if (lane == 0) { inv[w] = invn; ssq[w] = u; }
}

// ---------------------------------------------------------------------------
__global__ void init_ws(unsigned* __restrict__ kth, int* __restrict__ cnt,
                        unsigned* __restrict__ bar, float* __restrict__ out, int n_extra) {
    int t = blockIdx.x * blockDim.x + threadIdx.x;
    if (t < 32) { kth[t] = 0x7F800000u; cnt[t] = 0; bar[t] = 0u; }
    if (t < n_extra) out[Q_ROWS + t] = 1.0f;
}

// ---------------------------------------------------------------------------
__device__ __forceinline__ void t3ins(float (&t3)[3], float d) {
    float mx = fmaxf(fmaxf(t3[0], t3[1]), t3[2]);
    if (d < mx) {
        if (t3[0] == mx) t3[0] = d;
        else if (t3[1] == mx) t3[1] = d;
        else t3[2] = d;
    }
}

__device__ __forceinline__ float smean3(float a, float b, float c) {
    float lo = fminf(fminf(a, b), c);
    float hi = fmaxf(fmaxf(a, b), c);
    float md = fminf(fmaxf(a, b), fminf(fmaxf(b, c), fmaxf(a, c)));
    return ((lo + md) + hi) * (1.0f / 3.0f);
}

// ---------------------------------------------------------------------------
// Phase B: fp32 GEMM (raw dot, inv-scaled in epilogue) + per-row top-3.
// R3's proven full-line staging (8 lanes x 128B per row -> 56 MB FETCH) with
// XOR slot swizzle (write AND read) for bank-conflict-free LDS, single-buffered
// 36 KB LDS, launch_bounds(256,4) -> 4 blocks/CU.
__launch_bounds__(256, 4)
__global__ void knn_support_kernel(const float* __restrict__ qf, const float* __restrict__ sf,
                                   const float* __restrict__ inv_q, const float* __restrict__ inv_s,
                                   const float* __restrict__ qq, const float* __restrict__ pp,
                                   float* __restrict__ top3part) {
    __shared__ __align__(16) float As[BM * LDST];
    __shared__ __align__(16) float Bs[BM * LDST];

    int b0 = blockIdx.x;
    int rb = (b0 & 63) * BM;     // same-A blocks (all 16 cs) land on one XCD: (rb+64cs)%8 == rb%8
    int cs = b0 >> 6;
    int tid = threadIdx.x;
    int tx = tid & 15, ty = tid >> 4;

    float t3[8][3];
#pragma unroll
    for (int i = 0; i < 8; ++i) t3[i][0] = t3[i][1] = t3[i][2] = INFINITY;

    for (int ch = 0; ch < 2; ++ch) {
        int cb = cs * 256 + ch * 128;
        float acc[8][8];
#pragma unroll
        for (int i = 0; i < 8; ++i)
#pragma unroll
            for (int j = 0; j < 8; ++j) acc[i][j] = 0.0f;

        for (int kt = 0; kt < 8; ++kt) {
            int ko = kt * 32;
            __syncthreads();   // previous tile's readers done before overwrite
#pragma unroll
            for (int q = 0; q < 4; ++q) {
                int idx = q * 256 + tid;
                int row = idx >> 3, f4 = idx & 7;
                int slot = f4 ^ ((row >> 1) & 7);
                float4 a = *reinterpret_cast<const float4*>(qf + (size_t)(rb + row) * DIM + ko + f4 * 4);
                *reinterpret_cast<float4*>(As + row * LDST + (slot << 2)) = a;
                float4 b = *reinterpret_cast<const float4*>(sf + (size_t)(cb + row) * DIM + ko + f4 * 4);
                *reinterpret_cast<float4*>(Bs + row * LDST + (slot << 2)) = b;
            }
            __syncthreads();
#pragma unroll
            for (int K = 0; K < 8; ++K) {
                int sA = (K ^ (ty >> 1)) << 2;
                int sB = (K ^ (tx >> 1)) << 2;
                float4 av[8];
#pragma unroll
                for (int i = 0; i < 8; ++i)
                    av[i] = *reinterpret_cast<const float4*>(As + (ty + 16 * i) * LDST + sA);
#pragma unroll
                for (int jh = 0; jh < 2; ++jh) {
                    float4 bv[4];
#pragma unroll
                    for (int j2 = 0; j2 < 4; ++j2)
                        bv[j2] = *reinterpret_cast<const float4*>(Bs + (tx + 16 * (jh * 4 + j2)) * LDST + sB);
#pragma unroll
                    for (int i = 0; i < 8; ++i)
#pragma unroll
                        for (int j2 = 0; j2 < 4; ++j2) {
                            int j = jh * 4 + j2;
                            acc[i][j] += av[i].x * bv[j2].x;
                            acc[i][j] += av[i].y * bv[j2].y;
                            acc[i][j] += av[i].z * bv[j2].z;
                            acc[i][j] += av[i].w * bv[j2].w;
                        }
                }
            }
        }
        // epilogue for col-chunk: scale, distance, top-3
        float ivb[8], ppc[8];
#pragma unroll
        for (int j = 0; j < 8; ++j) {
            ivb[j] = inv_s[cb + tx + 16 * j];
            ppc[j] = pp[cb + tx + 16 * j];
        }
#pragma unroll
        for (int i = 0; i < 8; ++i) {
            int r = rb + ty + 16 * i;
            float iva = inv_q[r];
            float qqr = qq[r];
#pragma unroll
            for (int j = 0; j < 8; ++j) {
                float dot = acc[i][j] * iva * ivb[j];
                float d2 = qqr + ppc[j] - 2.0f * dot;
                float d = sqrtf(fmaxf(d2, 1e-12f));
                t3ins(t3[i], d);
            }
        }
    }

    // merge per-row top3 across the 16 tx lanes (in-wave butterfly)
#pragma unroll
    for (int off = 1; off < 16; off <<= 1) {
#pragma unroll
        for (int i = 0; i < 8; ++i) {
            float o0 = __shfl_xor(t3[i][0], off, 64);
            float o1 = __shfl_xor(t3[i][1], off, 64);
            float o2 = __shfl_xor(t3[i][2], off, 64);
            t3ins(t3[i], o0);
            t3ins(t3[i], o1);
            t3ins(t3[i], o2);
        }
    }
    if (tx == 0) {
#pragma unroll
        for (int i = 0; i < 8; ++i) {
            float* dst = top3part + ((size_t)cs * Q_ROWS + rb + ty + 16 * i) * 4;
            dst[0] = t3[i][0]; dst[1] = t3[i][1]; dst[2] = t3[i][2]; dst[3] = 0.0f;
        }
    }
}

// ---------------------------------------------------------------------------
// Phase C (unchanged from R5): 20 scan steps, one cooperative kernel, one
// relaxed-spin barrier per iteration; candidates = per-block argmin ties.
__global__ void iterate_select(const float* __restrict__ qf, const float* __restrict__ inv_q,
                               const float* __restrict__ qq, const float* __restrict__ top3part,
                               float* __restrict__ out, unsigned* __restrict__ kth,
                               int* __restrict__ cnt, unsigned* __restrict__ bar,
                               int* __restrict__ listI, float* __restrict__ listU) {
    __shared__ float t3s[CR][3];
    __shared__ float invs[CR], qqs[CR], scs[CR];
    __shared__ int kn[CR];
    __shared__ __align__(16) float qfc[DIM];
    __shared__ float red[CT / 64];
    __shared__ float bmin_sh;

    int tid = threadIdx.x;
    int rbase = blockIdx.x * CR;
    int lane = tid & 63, wv = tid >> 6;

    if (tid < CR) {
        int r = rbase + tid;
        float b3[3] = {INFINITY, INFINITY, INFINITY};
        for (int csq = 0; csq < COLSPLIT; ++csq) {
            const float* p = top3part + ((size_t)csq * Q_ROWS + r) * 4;
            t3ins(b3, p[0]); t3ins(b3, p[1]); t3ins(b3, p[2]);
        }
        t3s[tid][0] = b3[0]; t3s[tid][1] = b3[1]; t3s[tid][2] = b3[2];
        invs[tid] = inv_q[r];
        qqs[tid] = qq[r];
        kn[tid] = 0;
    }
    __syncthreads();

    for (int t = 0; t <= N_SEL; ++t) {
        if (t > 0) {
            float kv = __uint_as_float(
                __hip_atomic_load(&kth[t - 1], __ATOMIC_RELAXED, __HIP_MEMORY_SCOPE_AGENT));
            int m = __hip_atomic_load(&cnt[t - 1], __ATOMIC_RELAXED, __HIP_MEMORY_SCOPE_AGENT);
            if (m > LCAP) m = LCAP;
            for (int j = 0; j < m; ++j) {
                float u = __uint_as_float(__hip_atomic_load(
                    (unsigned*)&listU[(t - 1) * LCAP + j], __ATOMIC_RELAXED, __HIP_MEMORY_SCOPE_AGENT));
                if (!(u <= kv)) continue;
                int c = __hip_atomic_load(&listI[(t - 1) * LCAP + j],
                                          __ATOMIC_RELAXED, __HIP_MEMORY_SCOPE_AGENT);
                if (tid == 0 && c >= rbase && c < rbase + CR) kn[c - rbase] = 1;
                if (tid < DIM) qfc[tid] = qf[(size_t)c * DIM + tid] * inv_q[c];
                __syncthreads();
                float qqc = qq[c];
                int row = tid >> 2, sub = tid & 3;
                const float4* rp = reinterpret_cast<const float4*>(qf + (size_t)(rbase + row) * DIM);
                const float4* cp = reinterpret_cast<const float4*>(qfc);
                float si = invs[row];
                float d = 0.0f;
#pragma unroll
                for (int i2 = 0; i2 < 16; ++i2) {
                    float4 v = rp[sub + 4 * i2];
                    float4 w = cp[sub + 4 * i2];
                    d += (v.x * si) * w.x;
                    d += (v.y * si) * w.y;
                    d += (v.z * si) * w.z;
                    d += (v.w * si) * w.w;
                }
                d += __shfl_xor(d, 1, 64);
                d += __shfl_xor(d, 2, 64);
                if (sub == 0) {
                    float d2 = qqs[row] + qqc - 2.0f * d;
                    float dist = sqrtf(fmaxf(d2, 1e-12f));
                    float b3[3] = {t3s[row][0], t3s[row][1], t3s[row][2]};
                    t3ins(b3, dist);
                    t3s[row][0] = b3[0]; t3s[row][1] = b3[1]; t3s[row][2] = b3[2];
                }
                __syncthreads();
            }
            __syncthreads();
        }

        if (t == N_SEL) {
            if (tid < CR)
                out[rbase + tid] = 1.0f - smean3(t3s[tid][0], t3s[tid][1], t3s[tid][2]);
            return;
        }

        if (tid < CR)
            scs[tid] = kn[tid] ? INFINITY : smean3(t3s[tid][0], t3s[tid][1], t3s[tid][2]);
        __syncthreads();

        float mn = (tid < CR) ? scs[tid] : INFINITY;
#pragma unroll
        for (int o = 1; o < 64; o <<= 1) mn = fminf(mn, __shfl_xor(mn, o, 64));
        if (lane == 0) red[wv] = mn;
        __syncthreads();
        if (tid == 0) {
            float v = red[0];
#pragma unroll
            for (int i = 1; i < CT / 64; ++i) v = fminf(v, red[i]);
            bmin_sh = v;
            atomicMin(&kth[t], __float_as_uint(v));
        }
        __syncthreads();
        float bmin = bmin_sh;
        if (tid < CR && scs[tid] == bmin) {
            int pos = __hip_atomic_fetch_add(&cnt[t], 1, __ATOMIC_RELAXED, __HIP_MEMORY_SCOPE_AGENT);
            if (pos < LCAP) {
                __hip_atomic_store(&listI[t * LCAP + pos], rbase + tid,
                                   __ATOMIC_RELAXED, __HIP_MEMORY_SCOPE_AGENT);
                __hip_atomic_store((unsigned*)&listU[t * LCAP + pos], __float_as_uint(scs[tid]),
                                   __ATOMIC_RELAXED, __HIP_MEMORY_SCOPE_AGENT);
            }
        }
        __syncthreads();
        if (tid == 0) {
            __hip_atomic_fetch_add(&bar[t], 1u, __ATOMIC_RELEASE, __HIP_MEMORY_SCOPE_AGENT);
            while (__hip_atomic_load(&bar[t], __ATOMIC_RELAXED, __HIP_MEMORY_SCOPE_AGENT) < CB)
                __builtin_amdgcn_s_sleep(2);
            __threadfence();
        }
        __syncthreads();
    }
}

// ---------------------------------------------------------------------------
extern "C" void kernel_launch(void* const* d_in, const int* in_sizes, int n_in,
                              void* d_out, int out_size, void* d_ws, size_t ws_size,
                              hipStream_t stream) {
    const float* sfeat = (const float*)d_in[0];
    const float* qfeat = (const float*)d_in[2];
    float* out = (float*)d_out;

    float* ws = (float*)d_ws;
    float* inv_q = ws + WS_INV_Q;
    float* qq    = ws + WS_QQ;
    float* inv_s = ws + WS_INV_S;
    float* pp    = ws + WS_PP;
    float* top3p = ws + WS_TOP3P;
    unsigned* kth = (unsigned*)(ws + WS_KTH);
    int* cnt      = (int*)(ws + WS_CNT);
    unsigned* bar = (unsigned*)(ws + WS_BAR);
    int* listI    = (int*)(ws + WS_LI);
    float* listU  = ws + WS_LU;

    int n_extra = out_size - Q_ROWS;
    if (n_extra < 0) n_extra = 0;

    norm_rows<<<Q_ROWS * 64 / 256, 256, 0, stream>>>(qfeat, inv_q, qq, Q_ROWS);
    norm_rows<<<S_ROWS * 64 / 256, 256, 0, stream>>>(sfeat, inv_s, pp, S_ROWS);
    init_ws<<<32, 256, 0, stream>>>(kth, cnt, bar, out, n_extra);
    knn_support_kernel<<<64 * COLSPLIT, 256, 0, stream>>>(qfeat, sfeat, inv_q, inv_s, qq, pp, top3p);

    const float* a0 = qfeat; const float* a1 = inv_q; const float* a2 = qq;
    const float* a3 = top3p; float* a4 = out;
    unsigned* a5 = kth; int* a6 = cnt; unsigned* a7 = bar; int* a8 = listI; float* a9 = listU;
    void* cargs[] = {&a0, &a1, &a2, &a3, &a4, &a5, &a6, &a7, &a8, &a9};
    hipLaunchCooperativeKernel(iterate_select, dim3(CB), dim3(CT), cargs, 0, stream);
}

// Round 7
// 607.303 us; speedup vs baseline: 4.0089x; 2.7166x over previous
//
#include <hip/hip_runtime.h>
#include <hip/hip_bf16.h>

// Problem constants (fixed by reference setup_inputs)
#define S_ROWS 4096
#define Q_ROWS 8192
#define DIM 256
#define N_SEL 19       // selection events (20 scan steps)
#define COLSPLIT 16    // phase-B column splits (4096/16 = 256 cols per block)
#define BM 128         // phase-B rows per block
#define LDST 36        // LDS row stride (floats)
#define CB 64          // phase-C blocks
#define CT 512         // phase-C threads
#define CR 128         // phase-C rows per block
#define LCAP 128       // candidate list capacity per iteration

// Workspace layout (floats)
#define WS_INV_Q 0
#define WS_QQ    (WS_INV_Q + Q_ROWS)
#define WS_INV_S (WS_QQ + Q_ROWS)
#define WS_PP    (WS_INV_S + S_ROWS)
#define WS_TOP3P (WS_PP + S_ROWS)                  // [COLSPLIT][Q_ROWS][4]
#define WS_KTH   (WS_TOP3P + COLSPLIT * Q_ROWS * 4)
#define WS_CNT   (WS_KTH + 32)
#define WS_BAR   (WS_CNT + 32)
#define WS_LI    (WS_BAR + 32)                     // int [32*LCAP]
#define WS_LU    (WS_LI + 32 * LCAP)               // float[32*LCAP]

// ---------------------------------------------------------------------------
__global__ void norm_rows(const float* __restrict__ x, float* __restrict__ inv,
                          float* __restrict__ ssq, int nrows) {
    int w = (blockIdx.x * blockDim.x + threadIdx.x) >> 6;
    int lane = threadIdx.x & 63;
    if (w >= nrows) return;
    float4 v = reinterpret_cast<const float4*>(x + (size_t)w * DIM)[lane];
    float s = v.x * v.x + v.y * v.y + v.z * v.z + v.w * v.w;
#pragma unroll
    for (int o = 1; o < 64; o <<= 1) s += __shfl_xor(s, o, 64);
    float invn = 1.0f / sqrtf(s);
    float t = v.x * invn; float u = t * t;
    t = v.y * invn; u += t * t;
    t = v.z * invn; u += t * t;
    t = v.w * invn; u += t * t;
#pragma unroll
    for (int o = 1; o < 64; o <<= 1) u += __shfl_xor(u, o, 64);
    if (lane == 0) { inv[w] = invn; ssq[w] = u; }
}

// ---------------------------------------------------------------------------
__global__ void init_ws(unsigned* __restrict__ kth, int* __restrict__ cnt,
                        unsigned* __restrict__ bar, float* __restrict__ out, int n_extra) {
    int t = blockIdx.x * blockDim.x + threadIdx.x;
    if (t < 32) { kth[t] = 0x7F800000u; cnt[t] = 0; bar[t] = 0u; }
    if (t < n_extra) out[Q_ROWS + t] = 1.0f;
}

// ---------------------------------------------------------------------------
__device__ __forceinline__ void t3ins(float (&t3)[3], float d) {
    float mx = fmaxf(fmaxf(t3[0], t3[1]), t3[2]);
    if (d < mx) {
        if (t3[0] == mx) t3[0] = d;
        else if (t3[1] == mx) t3[1] = d;
        else t3[2] = d;
    }
}

__device__ __forceinline__ float smean3(float a, float b, float c) {
    float lo = fminf(fminf(a, b), c);
    float hi = fmaxf(fmaxf(a, b), c);
    float md = fminf(fmaxf(a, b), fminf(fmaxf(b, c), fmaxf(a, c)));
    return ((lo + md) + hi) * (1.0f / 3.0f);
}

// ---------------------------------------------------------------------------
// Phase B: fp32 GEMM (raw dot, inv-scaled in epilogue) + per-row top-3.
// Full-line staging (8 lanes x 128B per row), XOR slot swizzle write+read.
// Register-lean quadrant inner loop (peak live: acc64 + 12 float4) so that
// __launch_bounds__(256,3) (168-VGPR budget, 3 blocks/CU) does NOT spill.
// R5/R6 lesson: over-constrained launch_bounds spilled acc -> GB-scale
// scratch traffic (WRITE_SIZE 3.7GB). Check WRITE_SIZE first.
__launch_bounds__(256, 3)
__global__ void knn_support_kernel(const float* __restrict__ qf, const float* __restrict__ sf,
                                   const float* __restrict__ inv_q, const float* __restrict__ inv_s,
                                   const float* __restrict__ qq, const float* __restrict__ pp,
                                   float* __restrict__ top3part) {
    __shared__ __align__(16) float As[BM * LDST];
    __shared__ __align__(16) float Bs[BM * LDST];

    int b0 = blockIdx.x;
    int rb = (b0 & 63) * BM;     // same-A blocks (all 16 cs) land on one XCD: (rb+64cs)%8 == rb%8
    int cs = b0 >> 6;
    int tid = threadIdx.x;
    int tx = tid & 15, ty = tid >> 4;

    float t3[8][3];
#pragma unroll
    for (int i = 0; i < 8; ++i) t3[i][0] = t3[i][1] = t3[i][2] = INFINITY;

    for (int ch = 0; ch < 2; ++ch) {
        int cb = cs * 256 + ch * 128;
        float acc[8][8];
#pragma unroll
        for (int i = 0; i < 8; ++i)
#pragma unroll
            for (int j = 0; j < 8; ++j) acc[i][j] = 0.0f;

        for (int kt = 0; kt < 8; ++kt) {
            int ko = kt * 32;
            __syncthreads();   // previous tile's readers done before overwrite
#pragma unroll
            for (int q = 0; q < 4; ++q) {
                int idx = q * 256 + tid;
                int row = idx >> 3, f4 = idx & 7;
                int slot = f4 ^ ((row >> 1) & 7);
                float4 a = *reinterpret_cast<const float4*>(qf + (size_t)(rb + row) * DIM + ko + f4 * 4);
                *reinterpret_cast<float4*>(As + row * LDST + (slot << 2)) = a;
                float4 b = *reinterpret_cast<const float4*>(sf + (size_t)(cb + row) * DIM + ko + f4 * 4);
                *reinterpret_cast<float4*>(Bs + row * LDST + (slot << 2)) = b;
            }
            __syncthreads();
#pragma unroll
            for (int K = 0; K < 8; ++K) {
                int sA = ((K ^ (ty >> 1)) & 7) << 2;
                int sB = ((K ^ (tx >> 1)) & 7) << 2;
                float4 av[4], bva[4], bvb[4];
                // segment 1: i0-3 x j0-3
#pragma unroll
                for (int i = 0; i < 4; ++i)
                    av[i] = *reinterpret_cast<const float4*>(As + (ty + 16 * i) * LDST + sA);
#pragma unroll
                for (int j = 0; j < 4; ++j)
                    bva[j] = *reinterpret_cast<const float4*>(Bs + (tx + 16 * j) * LDST + sB);
#pragma unroll
                for (int i = 0; i < 4; ++i)
#pragma unroll
                    for (int j = 0; j < 4; ++j) {
                        acc[i][j] += av[i].x * bva[j].x;
                        acc[i][j] += av[i].y * bva[j].y;
                        acc[i][j] += av[i].z * bva[j].z;
                        acc[i][j] += av[i].w * bva[j].w;
                    }
                // segment 2: i0-3 x j4-7
#pragma unroll
                for (int j = 0; j < 4; ++j)
                    bvb[j] = *reinterpret_cast<const float4*>(Bs + (tx + 16 * (4 + j)) * LDST + sB);
#pragma unroll
                for (int i = 0; i < 4; ++i)
#pragma unroll
                    for (int j = 0; j < 4; ++j) {
                        acc[i][4 + j] += av[i].x * bvb[j].x;
                        acc[i][4 + j] += av[i].y * bvb[j].y;
                        acc[i][4 + j] += av[i].z * bvb[j].z;
                        acc[i][4 + j] += av[i].w * bvb[j].w;
                    }
                // segment 3: i4-7 x j4-7 (av overwritten)
#pragma unroll
                for (int i = 0; i < 4; ++i)
                    av[i] = *reinterpret_cast<const float4*>(As + (ty + 16 * (4 + i)) * LDST + sA);
#pragma unroll
                for (int i = 0; i < 4; ++i)
#pragma unroll
                    for (int j = 0; j < 4; ++j) {
                        acc[4 + i][4 + j] += av[i].x * bvb[j].x;
                        acc[4 + i][4 + j] += av[i].y * bvb[j].y;
                        acc[4 + i][4 + j] += av[i].z * bvb[j].z;
                        acc[4 + i][4 + j] += av[i].w * bvb[j].w;
                    }
                // segment 4: i4-7 x j0-3 (bva reloaded)
#pragma unroll
                for (int j = 0; j < 4; ++j)
                    bva[j] = *reinterpret_cast<const float4*>(Bs + (tx + 16 * j) * LDST + sB);
#pragma unroll
                for (int i = 0; i < 4; ++i)
#pragma unroll
                    for (int j = 0; j < 4; ++j) {
                        acc[4 + i][j] += av[i].x * bva[j].x;
                        acc[4 + i][j] += av[i].y * bva[j].y;
                        acc[4 + i][j] += av[i].z * bva[j].z;
                        acc[4 + i][j] += av[i].w * bva[j].w;
                    }
            }
        }
        // epilogue for col-chunk: scale, distance, top-3
        float ivb[8], ppc[8];
#pragma unroll
        for (int j = 0; j < 8; ++j) {
            ivb[j] = inv_s[cb + tx + 16 * j];
            ppc[j] = pp[cb + tx + 16 * j];
        }
#pragma unroll
        for (int i = 0; i < 8; ++i) {
            int r = rb + ty + 16 * i;
            float iva = inv_q[r];
            float qqr = qq[r];
#pragma unroll
            for (int j = 0; j < 8; ++j) {
                float dot = acc[i][j] * iva * ivb[j];
                float d2 = qqr + ppc[j] - 2.0f * dot;
                float d = sqrtf(fmaxf(d2, 1e-12f));
                t3ins(t3[i], d);
            }
        }
    }

    // merge per-row top3 across the 16 tx lanes (in-wave butterfly)
#pragma unroll
    for (int off = 1; off < 16; off <<= 1) {
#pragma unroll
        for (int i = 0; i < 8; ++i) {
            float o0 = __shfl_xor(t3[i][0], off, 64);
            float o1 = __shfl_xor(t3[i][1], off, 64);
            float o2 = __shfl_xor(t3[i][2], off, 64);
            t3ins(t3[i], o0);
            t3ins(t3[i], o1);
            t3ins(t3[i], o2);
        }
    }
    if (tx == 0) {
#pragma unroll
        for (int i = 0; i < 8; ++i) {
            float* dst = top3part + ((size_t)cs * Q_ROWS + rb + ty + 16 * i) * 4;
            dst[0] = t3[i][0]; dst[1] = t3[i][1]; dst[2] = t3[i][2]; dst[3] = 0.0f;
        }
    }
}

// ---------------------------------------------------------------------------
// Phase C (unchanged, proven): 20 scan steps, one cooperative kernel, one
// relaxed-spin barrier per iteration; candidates = per-block argmin ties.
__global__ void iterate_select(const float* __restrict__ qf, const float* __restrict__ inv_q,
                               const float* __restrict__ qq, const float* __restrict__ top3part,
                               float* __restrict__ out, unsigned* __restrict__ kth,
                               int* __restrict__ cnt, unsigned* __restrict__ bar,
                               int* __restrict__ listI, float* __restrict__ listU) {
    __shared__ float t3s[CR][3];
    __shared__ float invs[CR], qqs[CR], scs[CR];
    __shared__ int kn[CR];
    __shared__ __align__(16) float qfc[DIM];
    __shared__ float red[CT / 64];
    __shared__ float bmin_sh;

    int tid = threadIdx.x;
    int rbase = blockIdx.x * CR;
    int lane = tid & 63, wv = tid >> 6;

    if (tid < CR) {
        int r = rbase + tid;
        float b3[3] = {INFINITY, INFINITY, INFINITY};
        for (int csq = 0; csq < COLSPLIT; ++csq) {
            const float* p = top3part + ((size_t)csq * Q_ROWS + r) * 4;
            t3ins(b3, p[0]); t3ins(b3, p[1]); t3ins(b3, p[2]);
        }
        t3s[tid][0] = b3[0]; t3s[tid][1] = b3[1]; t3s[tid][2] = b3[2];
        invs[tid] = inv_q[r];
        qqs[tid] = qq[r];
        kn[tid] = 0;
    }
    __syncthreads();

    for (int t = 0; t <= N_SEL; ++t) {
        if (t > 0) {
            float kv = __uint_as_float(
                __hip_atomic_load(&kth[t - 1], __ATOMIC_RELAXED, __HIP_MEMORY_SCOPE_AGENT));
            int m = __hip_atomic_load(&cnt[t - 1], __ATOMIC_RELAXED, __HIP_MEMORY_SCOPE_AGENT);
            if (m > LCAP) m = LCAP;
            for (int j = 0; j < m; ++j) {
                float u = __uint_as_float(__hip_atomic_load(
                    (unsigned*)&listU[(t - 1) * LCAP + j], __ATOMIC_RELAXED, __HIP_MEMORY_SCOPE_AGENT));
                if (!(u <= kv)) continue;
                int c = __hip_atomic_load(&listI[(t - 1) * LCAP + j],
                                          __ATOMIC_RELAXED, __HIP_MEMORY_SCOPE_AGENT);
                if (tid == 0 && c >= rbase && c < rbase + CR) kn[c - rbase] = 1;
                if (tid < DIM) qfc[tid] = qf[(size_t)c * DIM + tid] * inv_q[c];
                __syncthreads();
                float qqc = qq[c];
                int row = tid >> 2, sub = tid & 3;
                const float4* rp = reinterpret_cast<const float4*>(qf + (size_t)(rbase + row) * DIM);
                const float4* cp = reinterpret_cast<const float4*>(qfc);
                float si = invs[row];
                float d = 0.0f;
#pragma unroll
                for (int i2 = 0; i2 < 16; ++i2) {
                    float4 v = rp[sub + 4 * i2];
                    float4 w = cp[sub + 4 * i2];
                    d += (v.x * si) * w.x;
                    d += (v.y * si) * w.y;
                    d += (v.z * si) * w.z;
                    d += (v.w * si) * w.w;
                }
                d += __shfl_xor(d, 1, 64);
                d += __shfl_xor(d, 2, 64);
                if (sub == 0) {
                    float d2 = qqs[row] + qqc - 2.0f * d;
                    float dist = sqrtf(fmaxf(d2, 1e-12f));
                    float b3[3] = {t3s[row][0], t3s[row][1], t3s[row][2]};
                    t3ins(b3, dist);
                    t3s[row][0] = b3[0]; t3s[row][1] = b3[1]; t3s[row][2] = b3[2];
                }
                __syncthreads();
            }
            __syncthreads();
        }

        if (t == N_SEL) {
            if (tid < CR)
                out[rbase + tid] = 1.0f - smean3(t3s[tid][0], t3s[tid][1], t3s[tid][2]);
            return;
        }

        if (tid < CR)
            scs[tid] = kn[tid] ? INFINITY : smean3(t3s[tid][0], t3s[tid][1], t3s[tid][2]);
        __syncthreads();

        float mn = (tid < CR) ? scs[tid] : INFINITY;
#pragma unroll
        for (int o = 1; o < 64; o <<= 1) mn = fminf(mn, __shfl_xor(mn, o, 64));
        if (lane == 0) red[wv] = mn;
        __syncthreads();
        if (tid == 0) {
            float v = red[0];
#pragma unroll
            for (int i = 1; i < CT / 64; ++i) v = fminf(v, red[i]);
            bmin_sh = v;
            atomicMin(&kth[t], __float_as_uint(v));
        }
        __syncthreads();
        float bmin = bmin_sh;
        if (tid < CR && scs[tid] == bmin) {
            int pos = __hip_atomic_fetch_add(&cnt[t], 1, __ATOMIC_RELAXED, __HIP_MEMORY_SCOPE_AGENT);
            if (pos < LCAP) {
                __hip_atomic_store(&listI[t * LCAP + pos], rbase + tid,
                                   __ATOMIC_RELAXED, __HIP_MEMORY_SCOPE_AGENT);
                __hip_atomic_store((unsigned*)&listU[t * LCAP + pos], __float_as_uint(scs[tid]),
                                   __ATOMIC_RELAXED, __HIP_MEMORY_SCOPE_AGENT);
            }
        }
        __syncthreads();
        if (tid == 0) {
            __hip_atomic_fetch_add(&bar[t], 1u, __ATOMIC_RELEASE, __HIP_MEMORY_SCOPE_AGENT);
            while (__hip_atomic_load(&bar[t], __ATOMIC_RELAXED, __HIP_MEMORY_SCOPE_AGENT) < CB)
                __builtin_amdgcn_s_sleep(2);
            __threadfence();
        }
        __syncthreads();
    }
}

// ---------------------------------------------------------------------------
extern "C" void kernel_launch(void* const* d_in, const int* in_sizes, int n_in,
                              void* d_out, int out_size, void* d_ws, size_t ws_size,
                              hipStream_t stream) {
    const float* sfeat = (const float*)d_in[0];
    const float* qfeat = (const float*)d_in[2];
    float* out = (float*)d_out;

    float* ws = (float*)d_ws;
    float* inv_q = ws + WS_INV_Q;
    float* qq    = ws + WS_QQ;
    float* inv_s = ws + WS_INV_S;
    float* pp    = ws + WS_PP;
    float* top3p = ws + WS_TOP3P;
    unsigned* kth = (unsigned*)(ws + WS_KTH);
    int* cnt      = (int*)(ws + WS_CNT);
    unsigned* bar = (unsigned*)(ws + WS_BAR);
    int* listI    = (int*)(ws + WS_LI);
    float* listU  = ws + WS_LU;

    int n_extra = out_size - Q_ROWS;
    if (n_extra < 0) n_extra = 0;

    norm_rows<<<Q_ROWS * 64 / 256, 256, 0, stream>>>(qfeat, inv_q, qq, Q_ROWS);
    norm_rows<<<S_ROWS * 64 / 256, 256, 0, stream>>>(sfeat, inv_s, pp, S_ROWS);
    init_ws<<<32, 256, 0, stream>>>(kth, cnt, bar, out, n_extra);
    knn_support_kernel<<<64 * COLSPLIT, 256, 0, stream>>>(qfeat, sfeat, inv_q, inv_s, qq, pp, top3p);

    const float* a0 = qfeat; const float* a1 = inv_q; const float* a2 = qq;
    const float* a3 = top3p; float* a4 = out;
    unsigned* a5 = kth; int* a6 = cnt; unsigned* a7 = bar; int* a8 = listI; float* a9 = listU;
    void* cargs[] = {&a0, &a1, &a2, &a3, &a4, &a5, &a6, &a7, &a8, &a9};
    hipLaunchCooperativeKernel(iterate_select, dim3(CB), dim3(CT), cargs, 0, stream);
}